// Round 3
// baseline (39.844 us; speedup 1.0000x reference)
//
#include <hip/hip_runtime.h>

#define B_ROWS 32768
#define C_COLS 1000
#define NF4 250                 // C_COLS / 4
#define HIST_BLOCKS 16
#define MAIN_BLOCKS 2048        // 8192 waves, 4 rows each

// --- histogram: per-block LDS counts, DIRECT store of partials (no zeroing,
//     no global atomics). main sums the 16 partial rows when staging LDS. ---
__global__ __launch_bounds__(256) void bsl_hist(const int* __restrict__ target,
                                                float* __restrict__ freq_part) {
    __shared__ unsigned int lh[C_COLS];
    const int tid = threadIdx.x;
    for (int i = tid; i < C_COLS; i += 256) lh[i] = 0u;
    __syncthreads();
    const int4* t4 = reinterpret_cast<const int4*>(target + blockIdx.x * 2048);
    #pragma unroll
    for (int k = 0; k < 2; ++k) {
        int4 v = t4[tid + k * 256];
        atomicAdd(&lh[v.x], 1u);
        atomicAdd(&lh[v.y], 1u);
        atomicAdd(&lh[v.z], 1u);
        atomicAdd(&lh[v.w], 1u);
    }
    __syncthreads();
    float* dst = freq_part + blockIdx.x * C_COLS;
    for (int i = tid; i < C_COLS; i += 256) dst[i] = (float)lh[i];
}

// --- main: one wave per 4 contiguous rows, 2-row unroll (8 loads in flight),
//     no barriers / atomics in the hot path ---
__global__ __launch_bounds__(256) void bsl_main(const float* __restrict__ pred,
                                                const int* __restrict__ target,
                                                const float* __restrict__ freq_part,
                                                float* __restrict__ partials) {
    __shared__ float sfreq[C_COLS];
    __shared__ float swave[4];
    const int tid = threadIdx.x;
    const int lane = tid & 63;
    const int wib = tid >> 6;

    // stage freq = sum of 16 hist partials (L2-resident, 64 KB total)
    for (int i = tid; i < C_COLS; i += 256) {
        float s = 0.0f;
        #pragma unroll
        for (int b = 0; b < HIST_BLOCKS; ++b) s += freq_part[b * C_COLS + i];
        sfreq[i] = s;
    }
    __syncthreads();
    const float4* sf4 = reinterpret_cast<const float4*>(sfreq);

    const int base = (blockIdx.x * 4 + wib) * 4;   // 4 contiguous rows per wave
    float local = 0.0f;

    #pragma unroll
    for (int p = 0; p < 2; ++p) {
        const int r0 = base + p * 2;
        const int r1 = r0 + 1;
        const int t0 = target[r0], t1 = target[r1];
        const float4* p0 = reinterpret_cast<const float4*>(pred + (size_t)r0 * C_COLS);
        const float4* p1 = reinterpret_cast<const float4*>(pred + (size_t)r1 * C_COLS);
        const int t4i0 = t0 >> 2, tm0 = t0 & 3;
        const int t4i1 = t1 >> 2, tm1 = t1 & 3;

        float4 v0[4], v1[4];
        #pragma unroll
        for (int k = 0; k < 4; ++k) {
            const int j = k * 64 + lane;
            if (j < NF4) v0[k] = p0[j];
        }
        #pragma unroll
        for (int k = 0; k < 4; ++k) {
            const int j = k * 64 + lane;
            if (j < NF4) v1[k] = p1[j];
        }

        float s0 = 0.0f, s1 = 0.0f, pt0 = 0.0f, pt1 = 0.0f;
        #pragma unroll
        for (int k = 0; k < 4; ++k) {
            const int j = k * 64 + lane;
            if (j < NF4) {
                const float4 f = sf4[j];
                const float4 a = v0[k];
                const float4 b = v1[k];
                s0 += __expf(a.x) * f.x + __expf(a.y) * f.y
                    + __expf(a.z) * f.z + __expf(a.w) * f.w;
                s1 += __expf(b.x) * f.x + __expf(b.y) * f.y
                    + __expf(b.z) * f.z + __expf(b.w) * f.w;
                if (j == t4i0)
                    pt0 = (tm0 & 1) ? ((tm0 & 2) ? a.w : a.y)
                                    : ((tm0 & 2) ? a.z : a.x);
                if (j == t4i1)
                    pt1 = (tm1 & 1) ? ((tm1 & 2) ? b.w : b.y)
                                    : ((tm1 & 2) ? b.z : b.x);
            }
        }
        // two independent butterfly chains, interleaved
        #pragma unroll
        for (int off = 32; off > 0; off >>= 1) {
            s0 += __shfl_xor(s0, off, 64);
            s1 += __shfl_xor(s1, off, 64);
        }
        const float ptb0 = __shfl(pt0, t4i0 & 63, 64);
        const float ptb1 = __shfl(pt1, t4i1 & 63, 64);
        local += logf(s0) - ptb0 - logf(sfreq[t0]);
        local += logf(s1) - ptb1 - logf(sfreq[t1]);
    }

    // `local` is identical across the wave; block-reduce the 4 wave values
    if (lane == 0) swave[wib] = local;
    __syncthreads();
    if (tid == 0)
        partials[blockIdx.x] = swave[0] + swave[1] + swave[2] + swave[3];
}

__global__ __launch_bounds__(256) void bsl_finalize(const float* __restrict__ partials,
                                                    float* __restrict__ out) {
    const int tid = threadIdx.x;
    float s = 0.0f;
    for (int i = tid; i < MAIN_BLOCKS; i += 256) s += partials[i];
    #pragma unroll
    for (int off = 32; off > 0; off >>= 1) s += __shfl_xor(s, off, 64);
    __shared__ float sw[4];
    if ((tid & 63) == 0) sw[tid >> 6] = s;
    __syncthreads();
    if (tid == 0) out[0] = (sw[0] + sw[1] + sw[2] + sw[3]) / (float)B_ROWS;
}

extern "C" void kernel_launch(void* const* d_in, const int* in_sizes, int n_in,
                              void* d_out, int out_size, void* d_ws, size_t ws_size,
                              hipStream_t stream) {
    const float* pred = (const float*)d_in[0];
    const int* target = (const int*)d_in[1];

    float* freq_part = (float*)d_ws;                      // [16][1000]
    float* partials  = freq_part + HIST_BLOCKS * C_COLS;  // [MAIN_BLOCKS]

    bsl_hist<<<HIST_BLOCKS, 256, 0, stream>>>(target, freq_part);
    bsl_main<<<MAIN_BLOCKS, 256, 0, stream>>>(pred, target, freq_part, partials);
    bsl_finalize<<<1, 256, 0, stream>>>(partials, (float*)d_out);
}

// Round 4
// 38.490 us; speedup vs baseline: 1.0352x; 1.0352x over previous
//
#include <hip/hip_runtime.h>

#define B_ROWS 32768
#define C_COLS 1000
#define NF4 250                 // C_COLS / 4
#define MAIN_BLOCKS 4096        // 16384 waves, 2 rows each

// --- histogram: per-block LDS counts, sparse global fp32 atomic flush ---
__global__ __launch_bounds__(256) void bsl_hist(const int* __restrict__ target,
                                                float* __restrict__ freq) {
    __shared__ unsigned int lh[C_COLS];
    const int tid = threadIdx.x;
    for (int i = tid; i < C_COLS; i += 256) lh[i] = 0u;
    __syncthreads();
    const int4* t4 = reinterpret_cast<const int4*>(target + blockIdx.x * 2048);
    #pragma unroll
    for (int k = 0; k < 2; ++k) {
        int4 v = t4[tid + k * 256];
        atomicAdd(&lh[v.x], 1u);
        atomicAdd(&lh[v.y], 1u);
        atomicAdd(&lh[v.z], 1u);
        atomicAdd(&lh[v.w], 1u);
    }
    __syncthreads();
    for (int i = tid; i < C_COLS; i += 256) {
        unsigned int c = lh[i];
        if (c) atomicAdd(&freq[i], (float)c);
    }
}

// --- main: one wave per 2 rows, 8 float4 loads in flight, interleaved
//     butterfly chains, no barriers/atomics in the hot path ---
__global__ __launch_bounds__(256) void bsl_main(const float* __restrict__ pred,
                                                const int* __restrict__ target,
                                                const float* __restrict__ freq,
                                                float* __restrict__ partials) {
    __shared__ float sfreq[C_COLS];
    __shared__ float swave[4];
    const int tid = threadIdx.x;
    const int lane = tid & 63;
    const int wib = tid >> 6;

    for (int i = tid; i < C_COLS; i += 256) sfreq[i] = freq[i];
    __syncthreads();
    const float4* sf4 = reinterpret_cast<const float4*>(sfreq);

    const int r0 = (blockIdx.x * 4 + wib) * 2;   // 2 contiguous rows per wave
    const int r1 = r0 + 1;
    const int t0 = target[r0], t1 = target[r1];
    const float4* p0 = reinterpret_cast<const float4*>(pred + (size_t)r0 * C_COLS);
    const float4* p1 = reinterpret_cast<const float4*>(pred + (size_t)r1 * C_COLS);
    const int t4i0 = t0 >> 2, tm0 = t0 & 3;
    const int t4i1 = t1 >> 2, tm1 = t1 & 3;

    // issue all 8 loads before any consumption
    float4 v0[4], v1[4];
    #pragma unroll
    for (int k = 0; k < 4; ++k) {
        const int j = k * 64 + lane;
        if (j < NF4) v0[k] = p0[j];
    }
    #pragma unroll
    for (int k = 0; k < 4; ++k) {
        const int j = k * 64 + lane;
        if (j < NF4) v1[k] = p1[j];
    }

    float s0 = 0.0f, s1 = 0.0f, pt0 = 0.0f, pt1 = 0.0f;
    #pragma unroll
    for (int k = 0; k < 4; ++k) {
        const int j = k * 64 + lane;
        if (j < NF4) {
            const float4 f = sf4[j];
            const float4 a = v0[k];
            const float4 b = v1[k];
            s0 += __expf(a.x) * f.x + __expf(a.y) * f.y
                + __expf(a.z) * f.z + __expf(a.w) * f.w;
            s1 += __expf(b.x) * f.x + __expf(b.y) * f.y
                + __expf(b.z) * f.z + __expf(b.w) * f.w;
            if (j == t4i0)
                pt0 = (tm0 & 1) ? ((tm0 & 2) ? a.w : a.y)
                                : ((tm0 & 2) ? a.z : a.x);
            if (j == t4i1)
                pt1 = (tm1 & 1) ? ((tm1 & 2) ? b.w : b.y)
                                : ((tm1 & 2) ? b.z : b.x);
        }
    }
    // two independent butterfly chains, interleaved
    #pragma unroll
    for (int off = 32; off > 0; off >>= 1) {
        s0 += __shfl_xor(s0, off, 64);
        s1 += __shfl_xor(s1, off, 64);
    }
    const float ptb0 = __shfl(pt0, t4i0 & 63, 64);
    const float ptb1 = __shfl(pt1, t4i1 & 63, 64);
    float local = logf(s0) - ptb0 - logf(sfreq[t0])
                + logf(s1) - ptb1 - logf(sfreq[t1]);

    // `local` is identical across the wave; block-reduce the 4 wave values
    if (lane == 0) swave[wib] = local;
    __syncthreads();
    if (tid == 0)
        partials[blockIdx.x] = swave[0] + swave[1] + swave[2] + swave[3];
}

__global__ __launch_bounds__(256) void bsl_finalize(const float* __restrict__ partials,
                                                    float* __restrict__ out) {
    const int tid = threadIdx.x;
    float s = 0.0f;
    for (int i = tid; i < MAIN_BLOCKS; i += 256) s += partials[i];
    #pragma unroll
    for (int off = 32; off > 0; off >>= 1) s += __shfl_xor(s, off, 64);
    __shared__ float sw[4];
    if ((tid & 63) == 0) sw[tid >> 6] = s;
    __syncthreads();
    if (tid == 0) out[0] = (sw[0] + sw[1] + sw[2] + sw[3]) / (float)B_ROWS;
}

extern "C" void kernel_launch(void* const* d_in, const int* in_sizes, int n_in,
                              void* d_out, int out_size, void* d_ws, size_t ws_size,
                              hipStream_t stream) {
    const float* pred = (const float*)d_in[0];
    const int* target = (const int*)d_in[1];

    float* freq     = (float*)d_ws;          // [1024] histogram
    float* partials = freq + 1024;           // [MAIN_BLOCKS]

    // freq must start at zero every call (hist accumulates into it)
    hipMemsetAsync(freq, 0, 1024 * sizeof(float), stream);

    bsl_hist<<<16, 256, 0, stream>>>(target, freq);
    bsl_main<<<MAIN_BLOCKS, 256, 0, stream>>>(pred, target, freq, partials);
    bsl_finalize<<<1, 256, 0, stream>>>(partials, (float*)d_out);
}